// Round 3
// baseline (492.817 us; speedup 1.0000x reference)
//
#include <hip/hip_runtime.h>
#include <math.h>

// ---------------------------------------------------------------------------
// YOLOv5-style loss, 3 layers, fp32.
// R7: R6 proved device work (~45us over 4 dispatches) is NOT the budget:
// dense-scan rewrite changed device time but total stayed 230.3us. R5 proved
// device deltas DO pass through (fused 188us -> +170 measured). So ~185us is
// poison fill (61us) + per-dispatch launch/drain overhead over 5 slots.
// Attack dispatch count: 2 dispatches total.
//   D1: 64B memset of barrier header (cnt/gen/fin).
//   D2: ONE persistent kernel, 1024 blocks x 256, normal launch (graph-
//       capturable, unlike R5's cooperative path):
//       phase0 grid-stride zero acc+winner+cnt -> gbar
//       phase1 grid-stride entries: CIoU/box/scatter/iou/tcls  -> gbar
//       phase2 grid-stride dense chunked scan (R6's proven layout)
//       last-arriving block combines and writes out.
// Co-residency: __launch_bounds__(256,4) caps VGPR<=128 -> capacity 8
// blocks/CU = 2048; we launch 1024 -> all resident under any skew.
// Barrier = device-scope atomics + threadfence (release-before-arrive,
// acquire-after-spin) — same semantics as R5's grid.sync, which passed.
// ---------------------------------------------------------------------------

#define EPS 1e-7f
#define BS 16
#define NA 3
#define NC 80

#define LOG2E 1.44269504088896340736f
#define LN2   0.69314718055994530942f

#define NBLOCKS 1024

// acc layout (floats, after 64B barrier header): box[3][32] obj[3][32] cls[3][32]
#define ACC_BOX 0
#define ACC_OBJ 96
#define ACC_CLS 192
#define ACC_FLOATS 288          // 1152 bytes, 16B-multiple

struct Layer {
    const float* pred;
    const int*   b;
    const int*   a;
    const int*   gj;
    const int*   gi;
    const int*   tcls;
    const float* tbox;
    const float* anc;
    unsigned int* winner;   // [48*g*g] cells, 0 = empty else entry_idx+1
    unsigned int* cnt;      // [48*g*g] entry multiplicity per cell
    float*        iou;      // [n] CIoU per entry
    int g;
    int n;
};

struct Args {
    Layer L[3];
    int e_cum0, e_cum1, e_cum2;   // entry prefix sums (n0, n0+n1, total)
    int s_cum0, s_cum1, s_cum2;   // scan-item prefix sums (nq*8 per layer)
    int nq0, nq1, nq2;            // cell-quads per layer
    uint4*    zbase;              // zero region: acc + winner + cnt
    int       zvec;               // #uint4
    unsigned* bar;                // [0]=cnt [1]=gen [2]=fin (64B memset)
    float*    acc;
};

// bce_with_logits(x, 0) via HW transcendentals: branchless, ~7 VALU ops
__device__ __forceinline__ float bce0(float x) {
    float t = __builtin_amdgcn_exp2f(-fabsf(x) * LOG2E);   // exp(-|x|)
    return fmaxf(x, 0.f) + LN2 * __builtin_amdgcn_logf(1.f + t);
}

// sigmoid via HW exp2 + rcp
__device__ __forceinline__ float fsigmoid(float x) {
    float e = __builtin_amdgcn_exp2f(-x * LOG2E);
    return __builtin_amdgcn_rcpf(1.f + e);
}

// 64-lane wave sum
__device__ __forceinline__ float wred(float v) {
    #pragma unroll
    for (int o = 32; o > 0; o >>= 1) v += __shfl_down(v, o, 64);
    return v;
}

// device-wide generation barrier: release-before-arrive, acquire-after-spin
__device__ __forceinline__ void gbar(unsigned* bar, unsigned nb) {
    __syncthreads();
    if (threadIdx.x == 0) {
        __threadfence();                       // release my phase's writes
        unsigned g = __hip_atomic_load(&bar[1], __ATOMIC_RELAXED,
                                       __HIP_MEMORY_SCOPE_AGENT);
        unsigned a = __hip_atomic_fetch_add(&bar[0], 1u, __ATOMIC_ACQ_REL,
                                            __HIP_MEMORY_SCOPE_AGENT);
        if (a == nb - 1u) {
            __hip_atomic_store(&bar[0], 0u, __ATOMIC_RELAXED,
                               __HIP_MEMORY_SCOPE_AGENT);
            __threadfence();
            __hip_atomic_fetch_add(&bar[1], 1u, __ATOMIC_RELEASE,
                                   __HIP_MEMORY_SCOPE_AGENT);
        } else {
            while (__hip_atomic_load(&bar[1], __ATOMIC_RELAXED,
                                     __HIP_MEMORY_SCOPE_AGENT) == g)
                __builtin_amdgcn_s_sleep(8);
            __threadfence();                   // acquire others' writes
        }
    }
    __syncthreads();
}

__global__ void __launch_bounds__(256, 4) yolo_persistent(Args A, float* out) {
    const int tid  = (int)threadIdx.x;
    const int gid  = (int)blockIdx.x * 256 + tid;
    const int nthr = (int)gridDim.x * 256;
    const unsigned nb = gridDim.x;
    float* acc = A.acc;

    // ---- phase 0: zero acc + winner + cnt ---------------------------------
    {
        uint4 z = make_uint4(0u, 0u, 0u, 0u);
        for (int i = gid; i < A.zvec; i += nthr) A.zbase[i] = z;
    }
    gbar(A.bar, nb);

    // ---- phase 1: per-entry CIoU + box + scatter + tcls gather ------------
    {
        float bx0 = 0.f, bx1 = 0.f, bx2 = 0.f;
        float ng0 = 0.f, ng1 = 0.f, ng2 = 0.f;
        for (int jg = gid; jg < A.e_cum2; jg += nthr) {
            int layer, j;
            if (jg < A.e_cum0)      { layer = 0; j = jg; }
            else if (jg < A.e_cum1) { layer = 1; j = jg - A.e_cum0; }
            else                    { layer = 2; j = jg - A.e_cum1; }
            const Layer& L = A.L[layer];
            int b  = L.b[j],  a  = L.a[j];
            int gy = L.gj[j], gx = L.gi[j];
            int g = L.g, gg = g * g;
            int q = b * NA + a;
            const float* base = L.pred + ((size_t)(q * 85) * gg + (size_t)gy * g + gx);
            float px = base[0];
            float py = base[gg];
            float pw = base[2 * (size_t)gg];
            float ph = base[3 * (size_t)gg];
            // decode
            float cx = 2.f * fsigmoid(px) - 0.5f;
            float cy = 2.f * fsigmoid(py) - 0.5f;
            float sw = 2.f * fsigmoid(pw);
            float sh = 2.f * fsigmoid(ph);
            float bw = sw * sw * L.anc[2 * j];
            float bh = sh * sh * L.anc[2 * j + 1];
            float fg = (float)g;
            float tx = L.tbox[4 * j + 0] * fg - (float)gx;
            float ty = L.tbox[4 * j + 1] * fg - (float)gy;
            float tw = L.tbox[4 * j + 2] * fg;
            float th = L.tbox[4 * j + 3] * fg;
            // CIoU
            float b1x1 = cx - bw * 0.5f, b1x2 = cx + bw * 0.5f;
            float b1y1 = cy - bh * 0.5f, b1y2 = cy + bh * 0.5f;
            float b2x1 = tx - tw * 0.5f, b2x2 = tx + tw * 0.5f;
            float b2y1 = ty - th * 0.5f, b2y2 = ty + th * 0.5f;
            float iw = fminf(b1x2, b2x2) - fmaxf(b1x1, b2x1);
            float ih = fminf(b1y2, b2y2) - fmaxf(b1y1, b2y1);
            float inter = fmaxf(iw, 0.f) * fmaxf(ih, 0.f);
            float w1 = b1x2 - b1x1, h1 = b1y2 - b1y1 + EPS;
            float w2 = b2x2 - b2x1, h2 = b2y2 - b2y1 + EPS;
            float uni = w1 * h1 + w2 * h2 - inter + EPS;
            float iou = inter / uni;
            float cw  = fmaxf(b1x2, b2x2) - fminf(b1x1, b2x1);
            float chh = fmaxf(b1y2, b2y2) - fminf(b1y1, b2y1);
            float c2  = cw * cw + chh * chh + EPS;
            float dx = b2x1 + b2x2 - b1x1 - b1x2;
            float dy = b2y1 + b2y2 - b1y1 - b1y2;
            float rho2 = (dx * dx + dy * dy) * 0.25f;
            float dv = atanf(w2 / h2) - atanf(w1 / h1);
            float v = (4.f / (float)(M_PI * M_PI)) * dv * dv;
            float alpha = v / (v - iou + (1.f + EPS));
            float ciou = iou - (rho2 / c2 + v * alpha);
            L.iou[j] = ciou;
            int cell = q * gg + gy * g + gx;
            atomicMax(&L.winner[cell], (unsigned int)(j + 1));
            atomicAdd(&L.cnt[cell], 1u);
            float bc = 1.f - ciou;
            // class positive term: bce(x,1) = bce(x,0) - x  -> subtract x[tcls]
            float nc = base[(size_t)(5 + L.tcls[j]) * gg];
            bx0 += (layer == 0) ? bc : 0.f;
            bx1 += (layer == 1) ? bc : 0.f;
            bx2 += (layer == 2) ? bc : 0.f;
            ng0 += (layer == 0) ? nc : 0.f;
            ng1 += (layer == 1) ? nc : 0.f;
            ng2 += (layer == 2) ? nc : 0.f;
        }
        bx0 = wred(bx0); bx1 = wred(bx1); bx2 = wred(bx2);
        ng0 = wred(ng0); ng1 = wred(ng1); ng2 = wred(ng2);
        if ((tid & 63) == 0) {
            int slot = (((int)blockIdx.x << 2) + (tid >> 6)) & 31;
            if (bx0 != 0.f) atomicAdd(&acc[ACC_BOX + 0 * 32 + slot], bx0);
            if (bx1 != 0.f) atomicAdd(&acc[ACC_BOX + 1 * 32 + slot], bx1);
            if (bx2 != 0.f) atomicAdd(&acc[ACC_BOX + 2 * 32 + slot], bx2);
            if (ng0 != 0.f) atomicAdd(&acc[ACC_CLS + 0 * 32 + slot], -ng0);
            if (ng1 != 0.f) atomicAdd(&acc[ACC_CLS + 1 * 32 + slot], -ng1);
            if (ng2 != 0.f) atomicAdd(&acc[ACC_CLS + 2 * 32 + slot], -ng2);
        }
    }
    gbar(A.bar, nb);

    // ---- phase 2: dense chunked scan (R6's proven layout, grid-stride) ----
    {
        // preload per-layer fields into registers (avoid dynamic kernarg)
        const float*    P0 = A.L[0].pred,   *P1 = A.L[1].pred,   *P2 = A.L[2].pred;
        const unsigned* C0 = A.L[0].cnt,    *C1 = A.L[1].cnt,    *C2 = A.L[2].cnt;
        const unsigned* W0 = A.L[0].winner, *W1 = A.L[1].winner, *W2 = A.L[2].winner;
        const float*    I0 = A.L[0].iou,    *I1 = A.L[1].iou,    *I2 = A.L[2].iou;
        const int GG0 = A.L[0].g * A.L[0].g;
        const int GG1 = A.L[1].g * A.L[1].g;
        const int GG2 = A.L[2].g * A.L[2].g;
        float ob0 = 0.f, ob1 = 0.f, ob2 = 0.f;
        float cl0 = 0.f, cl1 = 0.f, cl2 = 0.f;

        for (int it = gid; it < A.s_cum2; it += nthr) {
            int layer, r;
            if (it < A.s_cum0)      { layer = 0; r = it; }
            else if (it < A.s_cum1) { layer = 1; r = it - A.s_cum0; }
            else                    { layer = 2; r = it - A.s_cum1; }
            const float*    pred = (layer == 0) ? P0 : ((layer == 1) ? P1 : P2);
            const unsigned* cntp = (layer == 0) ? C0 : ((layer == 1) ? C1 : C2);
            const unsigned* winp = (layer == 0) ? W0 : ((layer == 1) ? W1 : W2);
            const float*    ioup = (layer == 0) ? I0 : ((layer == 1) ? I1 : I2);
            int gg = (layer == 0) ? GG0 : ((layer == 1) ? GG1 : GG2);
            int nq = (layer == 0) ? A.nq0 : ((layer == 1) ? A.nq1 : A.nq2);
            int chunk = r / nq;           // 0..7 -> channels 5+10c..5+10c+10
            int qi    = r - chunk * nq;   // consecutive threads -> consecutive quads
            int ci = qi * 4;
            int q  = ci / gg;
            int e  = ci - q * gg;
            uint4 c4 = *(const uint4*)(cntp + ci);
            float f0 = (float)c4.x, f1 = (float)c4.y;
            float f2 = (float)c4.z, f3 = (float)c4.w;
            const float* p = pred + (size_t)(q * 85 + 5 + 10 * chunk) * gg + e;
            float s0 = 0.f, s1 = 0.f;
            #pragma unroll
            for (int rr = 0; rr < 10; rr += 2) {
                float4 ya = *(const float4*)(p + (size_t)rr * gg);
                float4 yb = *(const float4*)(p + (size_t)(rr + 1) * gg);
                s0 += f0 * bce0(ya.x) + f1 * bce0(ya.y)
                    + f2 * bce0(ya.z) + f3 * bce0(ya.w);
                s1 += f0 * bce0(yb.x) + f1 * bce0(yb.y)
                    + f2 * bce0(yb.z) + f3 * bce0(yb.w);
            }
            float cc = s0 + s1;
            cl0 += (layer == 0) ? cc : 0.f;
            cl1 += (layer == 1) ? cc : 0.f;
            cl2 += (layer == 2) ? cc : 0.f;
            if (chunk == 0) {
                uint4 w4 = *(const uint4*)(winp + ci);
                const float* pb = pred + (size_t)(q * 85 + 4) * gg + e;
                float4 x4 = *(const float4*)pb;
                float os = bce0(x4.x) + bce0(x4.y) + bce0(x4.z) + bce0(x4.w);
                if (w4.x) os -= x4.x * fmaxf(ioup[w4.x - 1], 0.f);
                if (w4.y) os -= x4.y * fmaxf(ioup[w4.y - 1], 0.f);
                if (w4.z) os -= x4.z * fmaxf(ioup[w4.z - 1], 0.f);
                if (w4.w) os -= x4.w * fmaxf(ioup[w4.w - 1], 0.f);
                ob0 += (layer == 0) ? os : 0.f;
                ob1 += (layer == 1) ? os : 0.f;
                ob2 += (layer == 2) ? os : 0.f;
            }
        }
        ob0 = wred(ob0); ob1 = wred(ob1); ob2 = wred(ob2);
        cl0 = wred(cl0); cl1 = wred(cl1); cl2 = wred(cl2);
        if ((tid & 63) == 0) {
            int slot = (((int)blockIdx.x << 2) + (tid >> 6)) & 31;
            if (ob0 != 0.f) atomicAdd(&acc[ACC_OBJ + 0 * 32 + slot], ob0);
            if (ob1 != 0.f) atomicAdd(&acc[ACC_OBJ + 1 * 32 + slot], ob1);
            if (ob2 != 0.f) atomicAdd(&acc[ACC_OBJ + 2 * 32 + slot], ob2);
            if (cl0 != 0.f) atomicAdd(&acc[ACC_CLS + 0 * 32 + slot], cl0);
            if (cl1 != 0.f) atomicAdd(&acc[ACC_CLS + 1 * 32 + slot], cl1);
            if (cl2 != 0.f) atomicAdd(&acc[ACC_CLS + 2 * 32 + slot], cl2);
        }
    }

    // ---- finish: last-arriving block combines -----------------------------
    __shared__ int is_last;
    __shared__ float part[9];
    __syncthreads();
    if (tid == 0) {
        __threadfence();                       // release my acc atomics
        unsigned c = __hip_atomic_fetch_add(&A.bar[2], 1u, __ATOMIC_ACQ_REL,
                                            __HIP_MEMORY_SCOPE_AGENT);
        is_last = (c == nb - 1u);
        if (is_last) __threadfence();          // acquire everyone's atomics
    }
    __syncthreads();
    if (is_last) {
        if (tid < 9) {
            int l = tid % 3, qn = tid / 3;     // qn: 0=box 1=obj 2=cls
            const float* s = &acc[qn * 96 + l * 32];
            float v = 0.f;
            #pragma unroll
            for (int k = 0; k < 32; ++k) v += s[k];
            part[tid] = v;
        }
        __syncthreads();
        if (tid == 0) {
            float n0 = (float)A.L[0].n, n1 = (float)A.L[1].n, n2 = (float)A.L[2].n;
            float c0 = (float)(BS * NA) * (float)(A.L[0].g * A.L[0].g);
            float c1 = (float)(BS * NA) * (float)(A.L[1].g * A.L[1].g);
            float c2 = (float)(BS * NA) * (float)(A.L[2].g * A.L[2].g);
            float box_l = part[0] / n0 + part[1] / n1 + part[2] / n2;
            float obj_l = 0.4f * part[3] / c0 + 1.0f * part[4] / c1
                        + 4.0f * part[5] / c2;
            float cls_l = part[6] / (n0 * NC) + part[7] / (n1 * NC)
                        + part[8] / (n2 * NC);
            out[0] = 0.05f * box_l + 1.0f * obj_l + 0.5f * cls_l;
        }
    }
}

extern "C" void kernel_launch(void* const* d_in, const int* in_sizes, int n_in,
                              void* d_out, int out_size, void* d_ws, size_t ws_size,
                              hipStream_t stream) {
    (void)n_in; (void)out_size; (void)ws_size;
    char* ws = (char*)d_ws;

    Args A;
    int n[3], g[3], cells[3];
    // bytes 0..63: barrier header (cnt, gen, fin) -- memset'd host-side
    // bytes 64..64+1151: acc partial-sum slots    -- zeroed in phase0
    size_t off = 64 + ACC_FLOATS * 4;
    size_t winner_off[3], cnt_off[3], iou_off[3];

    for (int i = 0; i < 3; ++i) {
        n[i] = in_sizes[8 * i + 1];
        int gg = in_sizes[8 * i] / (BS * 255);
        int gv = (int)(sqrt((double)gg) + 0.5);
        g[i] = gv;
        cells[i] = BS * NA * gv * gv;
        winner_off[i] = off; off += (size_t)cells[i] * 4;
        cnt_off[i]    = off; off += (size_t)cells[i] * 4;
    }
    size_t zero_end = off;                 // acc + winner + cnt
    for (int i = 0; i < 3; ++i) { iou_off[i] = off; off += (size_t)n[i] * 4; }

    for (int i = 0; i < 3; ++i) {
        Layer& L = A.L[i];
        L.pred = (const float*)d_in[8 * i + 0];
        L.b    = (const int*)  d_in[8 * i + 1];
        L.a    = (const int*)  d_in[8 * i + 2];
        L.gj   = (const int*)  d_in[8 * i + 3];
        L.gi   = (const int*)  d_in[8 * i + 4];
        L.tbox = (const float*)d_in[8 * i + 5];
        L.tcls = (const int*)  d_in[8 * i + 6];
        L.anc  = (const float*)d_in[8 * i + 7];
        L.winner = (unsigned int*)(ws + winner_off[i]);
        L.cnt    = (unsigned int*)(ws + cnt_off[i]);
        L.iou    = (float*)(ws + iou_off[i]);
        L.g = g[i];
        L.n = n[i];
    }
    A.e_cum0 = n[0];
    A.e_cum1 = n[0] + n[1];
    A.e_cum2 = n[0] + n[1] + n[2];
    A.nq0 = cells[0] / 4;
    A.nq1 = cells[1] / 4;
    A.nq2 = cells[2] / 4;
    A.s_cum0 = A.nq0 * 8;
    A.s_cum1 = A.s_cum0 + A.nq1 * 8;
    A.s_cum2 = A.s_cum1 + A.nq2 * 8;
    A.zbase = (uint4*)(ws + 64);
    A.zvec  = (int)((zero_end - 64) / 16);
    A.bar   = (unsigned*)ws;
    A.acc   = (float*)(ws + 64);

    hipMemsetAsync(d_ws, 0, 64, stream);   // barrier header only
    yolo_persistent<<<NBLOCKS, 256, 0, stream>>>(A, (float*)d_out);
}

// Round 4
// 233.315 us; speedup vs baseline: 2.1122x; 2.1122x over previous
//
#include <hip/hip_runtime.h>
#include <math.h>

// ---------------------------------------------------------------------------
// YOLOv5-style loss, 3 layers, fp32.
// R8: R7's persistent-kernel experiment exposed a HW constant: same-address
// device-scope RMWs serialize at ~250ns (1024-block barrier = ~300us idle).
// Grid-wide sync and single-hot-counter tricks are dead ends; dispatch
// boundaries (~10us) are cheaper. Structure reverts to R6's proven
// 4-dispatch pipeline (memset -> entry -> scan -> final).
// New in R8: PER-WAVE gating of the class-channel loop. R4 showed per-LANE
// gating de-coalesces; per-WAVE gating (__any over the wave's 256-cell
// span) keeps 1KB contiguous transactions and skips the 10-channel loop for
// the ~50% of wave-spans with zero active cells -> class traffic ~halved.
// ---------------------------------------------------------------------------

#define EPS 1e-7f
#define BS 16
#define NA 3
#define NC 80

#define LOG2E 1.44269504088896340736f
#define LN2   0.69314718055994530942f

// accumulator layout (floats): [0..2]=box  [3..98]=obj 3x32  [99..194]=cls 3x32
#define ACC_OBJ 3
#define ACC_CLS 99
#define ACC_FLOATS 256          // rounded; header = 1024 bytes

struct Layer {
    const float* pred;
    const int*   b;
    const int*   a;
    const int*   gj;
    const int*   gi;
    const int*   tcls;
    const float* tbox;
    const float* anc;
    unsigned int* winner;   // [48*g*g] cells, 0 = empty else entry_idx+1
    unsigned int* cnt;      // [48*g*g] entry multiplicity per cell
    float*        iou;      // [n] CIoU per entry
    int g;
    int n;
};

struct Args {
    Layer L[3];
    int cum0;   // block-partition boundaries for the current launch
    int cum1;
};

__device__ __forceinline__ int pick_layer(const Args& A, int& lb) {
    int bid = blockIdx.x;
    if (bid < A.cum0) { lb = bid; return 0; }
    if (bid < A.cum1) { lb = bid - A.cum0; return 1; }
    lb = bid - A.cum1; return 2;
}

// reduce two independent sums across a 256-thread block
__device__ __forceinline__ void block_reduce256_2(float& a, float& b) {
    #pragma unroll
    for (int o = 32; o > 0; o >>= 1) {
        a += __shfl_down(a, o, 64);
        b += __shfl_down(b, o, 64);
    }
    __shared__ float sma[4], smb[4];
    int lane = threadIdx.x & 63;
    int wid  = threadIdx.x >> 6;
    if (lane == 0) { sma[wid] = a; smb[wid] = b; }
    __syncthreads();
    if (threadIdx.x == 0) {
        a = sma[0] + sma[1] + sma[2] + sma[3];
        b = smb[0] + smb[1] + smb[2] + smb[3];
    }
}

// bce_with_logits(x, 0) via HW transcendentals: branchless, ~7 VALU ops
__device__ __forceinline__ float bce0(float x) {
    float t = __builtin_amdgcn_exp2f(-fabsf(x) * LOG2E);   // exp(-|x|)
    return fmaxf(x, 0.f) + LN2 * __builtin_amdgcn_logf(1.f + t);
}

// sigmoid via HW exp2 + rcp
__device__ __forceinline__ float fsigmoid(float x) {
    float e = __builtin_amdgcn_exp2f(-x * LOG2E);
    return __builtin_amdgcn_rcpf(1.f + e);
}

// --- kernel 1: per-entry CIoU + box loss + winner/cnt scatter + tcls gather -
__global__ void entry_kernel(Args A, float* acc) {
    int lb; int layer = pick_layer(A, lb);
    const Layer L = A.L[layer];
    int j = lb * 256 + (int)threadIdx.x;
    float box_c = 0.f;
    float neg_c = 0.f;    // x[tcls] to subtract from cls sum
    if (j < L.n) {
        int b  = L.b[j],  a  = L.a[j];
        int gy = L.gj[j], gx = L.gi[j];
        int g = L.g, gg = g * g;
        int q = b * NA + a;
        const float* base = L.pred + ((size_t)(q * 85) * gg + (size_t)gy * g + gx);
        float px = base[0];
        float py = base[gg];
        float pw = base[2 * (size_t)gg];
        float ph = base[3 * (size_t)gg];
        // decode
        float cx = 2.f * fsigmoid(px) - 0.5f;
        float cy = 2.f * fsigmoid(py) - 0.5f;
        float sw = 2.f * fsigmoid(pw);
        float sh = 2.f * fsigmoid(ph);
        float bw = sw * sw * L.anc[2 * j];
        float bh = sh * sh * L.anc[2 * j + 1];
        float fg = (float)g;
        float tx = L.tbox[4 * j + 0] * fg - (float)gx;
        float ty = L.tbox[4 * j + 1] * fg - (float)gy;
        float tw = L.tbox[4 * j + 2] * fg;
        float th = L.tbox[4 * j + 3] * fg;
        // CIoU
        float b1x1 = cx - bw * 0.5f, b1x2 = cx + bw * 0.5f;
        float b1y1 = cy - bh * 0.5f, b1y2 = cy + bh * 0.5f;
        float b2x1 = tx - tw * 0.5f, b2x2 = tx + tw * 0.5f;
        float b2y1 = ty - th * 0.5f, b2y2 = ty + th * 0.5f;
        float iw = fminf(b1x2, b2x2) - fmaxf(b1x1, b2x1);
        float ih = fminf(b1y2, b2y2) - fmaxf(b1y1, b2y1);
        float inter = fmaxf(iw, 0.f) * fmaxf(ih, 0.f);
        float w1 = b1x2 - b1x1, h1 = b1y2 - b1y1 + EPS;
        float w2 = b2x2 - b2x1, h2 = b2y2 - b2y1 + EPS;
        float uni = w1 * h1 + w2 * h2 - inter + EPS;
        float iou = inter / uni;
        float cw  = fmaxf(b1x2, b2x2) - fminf(b1x1, b2x1);
        float chh = fmaxf(b1y2, b2y2) - fminf(b1y1, b2y1);
        float c2  = cw * cw + chh * chh + EPS;
        float dx = b2x1 + b2x2 - b1x1 - b1x2;
        float dy = b2y1 + b2y2 - b1y1 - b1y2;
        float rho2 = (dx * dx + dy * dy) * 0.25f;
        float dv = atanf(w2 / h2) - atanf(w1 / h1);
        float v = (4.f / (float)(M_PI * M_PI)) * dv * dv;
        float alpha = v / (v - iou + (1.f + EPS));
        float ciou = iou - (rho2 / c2 + v * alpha);
        L.iou[j] = ciou;
        int cell = q * gg + gy * g + gx;
        atomicMax(&L.winner[cell], (unsigned int)(j + 1));
        atomicAdd(&L.cnt[cell], 1u);
        box_c = 1.f - ciou;
        // class positive term: bce(x,1) = bce(x,0) - x  -> subtract x[tcls]
        neg_c = base[(size_t)(5 + L.tcls[j]) * gg];
    }
    block_reduce256_2(box_c, neg_c);
    if (threadIdx.x == 0) {
        atomicAdd(&acc[layer], box_c);
        atomicAdd(&acc[ACC_CLS + layer * 32 + (blockIdx.x & 31)], -neg_c);
    }
}

// --- kernel 2: DENSE channel scan with PER-WAVE gating --------------------
// Thread owns 4 consecutive cells (float4 column). Block = (cell-group,
// channel-chunk). Waves whose 256-cell span has no active cell skip the
// 10-channel loop entirely; active waves load all lanes (coalesced 1KB).
// Chunk 0 additionally handles objectness + winner correction (dense).
__global__ void scan_kernel(Args A, float* acc) {
    int lb; int layer = pick_layer(A, lb);
    const Layer L = A.L[layer];
    int gg = L.g * L.g;
    int cells = BS * NA * gg;
    int sb = (cells + 1023) >> 10;       // cell groups per chunk
    int group = lb % sb;                 // consecutive blocks -> consecutive groups
    int chunk = lb / sb;                 // 0..7, channels 5+10c .. 5+10c+10
    int ci = group * 1024 + (int)threadIdx.x * 4;
    float obj_s = 0.f, cls_s = 0.f;
    if (ci < cells) {
        int q = ci / gg;
        int e = ci - q * gg;
        uint4 c4 = *(const uint4*)(L.cnt + ci);
        const float* pbase = L.pred + (size_t)(q * 85) * gg + e;
        if (chunk == 0) {
            uint4 w4 = *(const uint4*)(L.winner + ci);
            float4 x4 = *(const float4*)(pbase + 4 * (size_t)gg);
            obj_s = bce0(x4.x) + bce0(x4.y) + bce0(x4.z) + bce0(x4.w);
            if (w4.x) obj_s -= x4.x * fmaxf(L.iou[w4.x - 1], 0.f);
            if (w4.y) obj_s -= x4.y * fmaxf(L.iou[w4.y - 1], 0.f);
            if (w4.z) obj_s -= x4.z * fmaxf(L.iou[w4.z - 1], 0.f);
            if (w4.w) obj_s -= x4.w * fmaxf(L.iou[w4.w - 1], 0.f);
        }
        // per-WAVE gate: skip the class loop only if the whole wave's
        // 256-cell span is inactive (keeps loads coalesced when active)
        int act = (int)(c4.x | c4.y | c4.z | c4.w);
        if (__any(act)) {
            float f0 = (float)c4.x, f1 = (float)c4.y;
            float f2 = (float)c4.z, f3 = (float)c4.w;
            const float* p = pbase + (size_t)(5 + 10 * chunk) * gg;
            float s0 = 0.f, s1 = 0.f;
            #pragma unroll
            for (int r = 0; r < 10; r += 2) {
                float4 ya = *(const float4*)(p + (size_t)r * gg);
                float4 yb = *(const float4*)(p + (size_t)(r + 1) * gg);
                s0 += f0 * bce0(ya.x) + f1 * bce0(ya.y)
                    + f2 * bce0(ya.z) + f3 * bce0(ya.w);
                s1 += f0 * bce0(yb.x) + f1 * bce0(yb.y)
                    + f2 * bce0(yb.z) + f3 * bce0(yb.w);
            }
            cls_s = s0 + s1;
        }
    }
    block_reduce256_2(obj_s, cls_s);
    if (threadIdx.x == 0) {
        int s = blockIdx.x & 31;
        if (chunk == 0)    atomicAdd(&acc[ACC_OBJ + layer * 32 + s], obj_s);
        if (cls_s != 0.f)  atomicAdd(&acc[ACC_CLS + layer * 32 + s], cls_s);
    }
}

// --- kernel 3: combine ------------------------------------------------------
__global__ void final_kernel(const float* acc, float* out,
                             int n0, int n1, int n2,
                             int c0, int c1, int c2) {
    float obj[3] = {0.f, 0.f, 0.f};
    float cls[3] = {0.f, 0.f, 0.f};
    for (int l = 0; l < 3; ++l) {
        for (int s = 0; s < 32; ++s) {
            obj[l] += acc[ACC_OBJ + l * 32 + s];
            cls[l] += acc[ACC_CLS + l * 32 + s];
        }
    }
    float box_l = acc[0] / (float)n0 + acc[1] / (float)n1 + acc[2] / (float)n2;
    float obj_l = 0.4f * obj[0] / (float)c0
                + 1.0f * obj[1] / (float)c1
                + 4.0f * obj[2] / (float)c2;
    float cls_l = cls[0] / ((float)n0 * NC)
                + cls[1] / ((float)n1 * NC)
                + cls[2] / ((float)n2 * NC);
    out[0] = 0.05f * box_l + 1.0f * obj_l + 0.5f * cls_l;
}

extern "C" void kernel_launch(void* const* d_in, const int* in_sizes, int n_in,
                              void* d_out, int out_size, void* d_ws, size_t ws_size,
                              hipStream_t stream) {
    (void)n_in; (void)out_size; (void)ws_size;
    char* ws = (char*)d_ws;

    Args A;
    int n[3], g[3], cells[3];
    size_t off = ACC_FLOATS * 4;           // 1KB header: partial-sum slots
    size_t winner_off[3], cnt_off[3], iou_off[3];

    for (int i = 0; i < 3; ++i) {
        n[i] = in_sizes[8 * i + 1];
        int gg = in_sizes[8 * i] / (BS * 255);
        int gv = (int)(sqrt((double)gg) + 0.5);
        g[i] = gv;
        cells[i] = BS * NA * gv * gv;
        winner_off[i] = off; off += (size_t)cells[i] * 4;
        cnt_off[i]    = off; off += (size_t)cells[i] * 4;
    }
    size_t zero_bytes = off;               // accumulators + winner + cnt
    for (int i = 0; i < 3; ++i) { iou_off[i] = off; off += (size_t)n[i] * 4; }

    for (int i = 0; i < 3; ++i) {
        Layer& L = A.L[i];
        L.pred = (const float*)d_in[8 * i + 0];
        L.b    = (const int*)  d_in[8 * i + 1];
        L.a    = (const int*)  d_in[8 * i + 2];
        L.gj   = (const int*)  d_in[8 * i + 3];
        L.gi   = (const int*)  d_in[8 * i + 4];
        L.tbox = (const float*)d_in[8 * i + 5];
        L.tcls = (const int*)  d_in[8 * i + 6];
        L.anc  = (const float*)d_in[8 * i + 7];
        L.winner = (unsigned int*)(ws + winner_off[i]);
        L.cnt    = (unsigned int*)(ws + cnt_off[i]);
        L.iou    = (float*)(ws + iou_off[i]);
        L.g = g[i];
        L.n = n[i];
    }
    float* acc = (float*)ws;

    hipMemsetAsync(d_ws, 0, zero_bytes, stream);

    // entry kernel: CIoU + scatter winner/cnt + tcls gather
    {
        int b0 = (n[0] + 255) / 256, b1 = (n[1] + 255) / 256, b2 = (n[2] + 255) / 256;
        A.cum0 = b0; A.cum1 = b0 + b1;
        entry_kernel<<<b0 + b1 + b2, 256, 0, stream>>>(A, acc);
    }
    // dense scan: (cell-group x 8 channel-chunks) blocks per layer
    {
        int s0 = ((cells[0] + 1023) / 1024) * 8;
        int s1 = ((cells[1] + 1023) / 1024) * 8;
        int s2 = ((cells[2] + 1023) / 1024) * 8;
        A.cum0 = s0; A.cum1 = s0 + s1;
        scan_kernel<<<s0 + s1 + s2, 256, 0, stream>>>(A, acc);
    }
    final_kernel<<<1, 1, 0, stream>>>(acc, (float*)d_out,
                                      n[0], n[1], n[2],
                                      cells[0], cells[1], cells[2]);
}